// Round 7
// baseline (467.969 us; speedup 1.0000x reference)
//
#include <hip/hip_runtime.h>
#include <hip/hip_bf16.h>

// ---------------------------------------------------------------------------
// TransformerBlock: B=4, T=2048, D=1024, H=16, HD=64
// Round 7: attention rewrite (was 100us, VALUBusy 52%, MfmaUtil 15% --
// instruction-overhead-bound). QT=128 per block (each wave 32 q-rows: same
// staging serves 2x MFMA), pointer-bump staging (no per-kt v_mad_u64 chains),
// paired V-transpose writes (8 ds_write_b32 vs 16 ds_write_b16), bk/bv frags
// read once per kt and reused across both mt passes. LDS 45KB -> 3 blocks/CU.
// GEMMs unchanged from round 6 (BK=64 block-rich / BK=128 grid-starved).
// ---------------------------------------------------------------------------

typedef __bf16 bf16;
typedef __attribute__((ext_vector_type(8))) __bf16 bf16x8;
typedef __attribute__((ext_vector_type(4))) __bf16 bf16x4;
typedef __attribute__((ext_vector_type(2))) __bf16 bf16x2;
typedef __attribute__((ext_vector_type(4))) float floatx4;

#define EXPC 0.18033688011112042f  // 0.125 * log2(e)

__device__ __forceinline__ void async_cp16(const bf16* g, bf16* l) {
  __builtin_amdgcn_global_load_lds(
      (const __attribute__((address_space(1))) void*)g,
      (__attribute__((address_space(3))) void*)l, 16, 0, 0);
}

// ---------------------------------------------------------------------------
// Transpose + convert: W (K x N fp32) -> WT (N x K bf16). z picks the matrix.
// ---------------------------------------------------------------------------
__global__ __launch_bounds__(256) void transpose_cvt4(
    const float* __restrict__ S0, const float* __restrict__ S1,
    const float* __restrict__ S2, const float* __restrict__ S3,
    bf16* __restrict__ D0, bf16* __restrict__ D1, bf16* __restrict__ D2,
    bf16* __restrict__ D3, int K, int N) {
  const float* W = (blockIdx.z == 0) ? S0 : (blockIdx.z == 1) ? S1
                   : (blockIdx.z == 2) ? S2 : S3;
  bf16* WT = (blockIdx.z == 0) ? D0 : (blockIdx.z == 1) ? D1
             : (blockIdx.z == 2) ? D2 : D3;
  __shared__ bf16 tile[32][33];
  const int tn = blockIdx.x;
  const int tk = blockIdx.y;
  const int t = threadIdx.x;
  const int row = t >> 3;
  const int c4 = (t & 7) * 4;

  const float* src = W + (size_t)(tk * 32 + row) * N + tn * 32 + c4;
  float4 v = *(const float4*)src;
  tile[row][c4 + 0] = (bf16)v.x;
  tile[row][c4 + 1] = (bf16)v.y;
  tile[row][c4 + 2] = (bf16)v.z;
  tile[row][c4 + 3] = (bf16)v.w;
  __syncthreads();
  bf16x4 o;
  o[0] = tile[c4 + 0][row];
  o[1] = tile[c4 + 1][row];
  o[2] = tile[c4 + 2][row];
  o[3] = tile[c4 + 3][row];
  *(bf16x4*)(WT + (size_t)(tn * 32 + row) * K + tk * 32 + c4) = o;
}

__global__ __launch_bounds__(256) void transpose_cvt(
    const float* __restrict__ W, bf16* __restrict__ WT, int K, int N) {
  __shared__ bf16 tile[32][33];
  const int tn = blockIdx.x;
  const int tk = blockIdx.y;
  const int t = threadIdx.x;
  const int row = t >> 3;
  const int c4 = (t & 7) * 4;

  const float* src = W + (size_t)(tk * 32 + row) * N + tn * 32 + c4;
  float4 v = *(const float4*)src;
  tile[row][c4 + 0] = (bf16)v.x;
  tile[row][c4 + 1] = (bf16)v.y;
  tile[row][c4 + 2] = (bf16)v.z;
  tile[row][c4 + 3] = (bf16)v.w;
  __syncthreads();
  bf16x4 o;
  o[0] = tile[c4 + 0][row];
  o[1] = tile[c4 + 1][row];
  o[2] = tile[c4 + 2][row];
  o[3] = tile[c4 + 3][row];
  *(bf16x4*)(WT + (size_t)(tn * 32 + row) * K + tk * 32 + c4) = o;
}

// ---------------------------------------------------------------------------
// LayerNorm: one block per row of 1024. fp32 in -> bf16 out.
// ---------------------------------------------------------------------------
__global__ __launch_bounds__(256) void ln_kernel(
    const float* __restrict__ x, const float* __restrict__ gamma,
    const float* __restrict__ beta, bf16* __restrict__ out) {
  const int row = blockIdx.x;
  const int t = threadIdx.x;
  const float* xr = x + (size_t)row * 1024;
  float4 v4 = *(const float4*)(xr + t * 4);
  float a[4] = {v4.x, v4.y, v4.z, v4.w};
  float s = a[0] + a[1] + a[2] + a[3];
  float ss = a[0] * a[0] + a[1] * a[1] + a[2] * a[2] + a[3] * a[3];
  for (int off = 1; off < 64; off <<= 1) {
    s += __shfl_xor(s, off);
    ss += __shfl_xor(ss, off);
  }
  __shared__ float red[8];
  const int wid = t >> 6, lane = t & 63;
  if (lane == 0) { red[wid] = s; red[wid + 4] = ss; }
  __syncthreads();
  s = red[0] + red[1] + red[2] + red[3];
  ss = red[4] + red[5] + red[6] + red[7];
  const float mean = s * (1.0f / 1024.0f);
  const float var = ss * (1.0f / 1024.0f) - mean * mean;
  const float rstd = rsqrtf(var + 1e-5f);
  bf16x4 o;
  for (int j = 0; j < 4; ++j) {
    float g = gamma[t * 4 + j];
    float b = beta[t * 4 + j];
    o[j] = (bf16)((a[j] - mean) * rstd * g + b);
  }
  *(bf16x4*)(out + (size_t)row * 1024 + t * 4) = o;
}

// fast exact-form tanh-gelu: gelu = x*t/(t+1), t = e^{2u}.
__device__ __forceinline__ float gelu_f(float x) {
  const float c = 0.7978845608028654f;
  float u = c * (x + 0.044715f * x * x * x);
  u = fminf(fmaxf(u, -10.0f), 10.0f);
  float t = __builtin_exp2f(u * 2.8853900817779268f);  // e^{2u}
  return x * t * __builtin_amdgcn_rcpf(t + 1.0f);
}

// ---------------------------------------------------------------------------
// GEMM (256 thr, 4 waves 2x2, each 64x64): C[M,N] = A[M,K] @ BT[N,K]^T.
// 128x128 tile, templated BK: 64 block-rich (3 blocks/CU), 128 grid-starved.
// BK>=64: 16B groups XOR-swizzled via the global gather (LDS dst linear).
// MODE 1: bf16 = gelu(C+bias); MODE 2: f32 = C+bias+resid; MODE 3: bf16 = C.
// ---------------------------------------------------------------------------
template <int MODE, int BK>
__global__ __launch_bounds__(256, 2) void gemm_bt(
    const bf16* __restrict__ A, const bf16* __restrict__ BT,
    const float* __restrict__ bias, const float* __restrict__ resid,
    void* __restrict__ out, int M, int N, int K) {
  __shared__ bf16 sA[128 * BK];
  __shared__ bf16 sB[128 * BK];
  constexpr int GPR = BK / 8;
  constexpr int CPT = GPR / 2;
  constexpr int RPI = 256 / GPR;
  constexpr int SW = (BK >= 64) ? 7 : 0;

  const int t = threadIdx.x;
  const int lane = t & 63, wid = t >> 6;
  const int waveM = wid >> 1, waveN = wid & 1;
  const int quad = lane >> 4, l16 = lane & 15;
  const size_t m0 = (size_t)blockIdx.x * 128;
  const size_t n0 = (size_t)blockIdx.y * 128;

  floatx4 acc[4][4] = {};

  const int r0 = t / GPR;
  const int gp = t % GPR;
  const int gsrc = gp ^ (r0 & SW);
  const bf16* Ag = A + (m0 + r0) * (size_t)K + gsrc * 8;
  const bf16* Bg = BT + (n0 + r0) * (size_t)K + gsrc * 8;
  bf16* sAp = sA + t * 8;
  bf16* sBp = sB + t * 8;

  for (int k0 = 0; k0 < K; k0 += BK) {
    __syncthreads();
#pragma unroll
    for (int it = 0; it < CPT; ++it) {
      async_cp16(Ag + k0 + (size_t)(it * RPI) * K, sAp + it * 2048);
      async_cp16(Bg + k0 + (size_t)(it * RPI) * K, sBp + it * 2048);
    }
    __syncthreads();
#pragma unroll
    for (int ks = 0; ks < BK / 32; ++ks) {
      bf16x8 af[4], bfv[4];
#pragma unroll
      for (int i = 0; i < 4; ++i) {
        const int rowA = waveM * 64 + i * 16 + l16;
        const int g = ((ks * 4 + quad) ^ (l16 & SW)) * 8;
        af[i] = *(const bf16x8*)&sA[rowA * BK + g];
        const int rowB = waveN * 64 + i * 16 + l16;
        bfv[i] = *(const bf16x8*)&sB[rowB * BK + g];
      }
#pragma unroll
      for (int mt = 0; mt < 4; ++mt)
#pragma unroll
        for (int nt = 0; nt < 4; ++nt)
          acc[mt][nt] = __builtin_amdgcn_mfma_f32_16x16x32_bf16(
              af[mt], bfv[nt], acc[mt][nt], 0, 0, 0);
    }
  }

#pragma unroll
  for (int mt = 0; mt < 4; ++mt) {
#pragma unroll
    for (int nt = 0; nt < 4; ++nt) {
      const size_t row_base = m0 + waveM * 64 + mt * 16 + quad * 4;
      const size_t col = n0 + waveN * 64 + nt * 16 + l16;
#pragma unroll
      for (int r = 0; r < 4; ++r) {
        const size_t row = row_base + r;
        float v = acc[mt][nt][r];
        if (MODE == 1) {
          v = gelu_f(v + bias[col]);
          ((bf16*)out)[row * N + col] = (bf16)v;
        } else if (MODE == 2) {
          v += bias[col] + resid[row * N + col];
          ((float*)out)[row * N + col] = v;
        } else {
          ((bf16*)out)[row * N + col] = (bf16)v;
        }
      }
    }
  }
}

// ---------------------------------------------------------------------------
// Flash-style causal attention, QT=128 per block.
// Each of 4 waves owns 32 q-rows (2 mt frags). Fixed-max softmax (scores
// bounded). K/V staged per 64-row k-tile with pointer-bump addressing;
// V transposed into sVt with PAIRED b32 writes (cols 2r,2r+1 packed),
// XOR-swizzled by (hd&56). bk/bv frags read once per kt, reused across mt.
// sP per-wave 16 rows, two mt passes (same-wave LDS ordering, no barrier).
// LDS: sQ 18K + sK 9K + sVt 9K + sP 9K = 45KB -> 3 blocks/CU.
// ---------------------------------------------------------------------------
__global__ __launch_bounds__(256) void attn_kernel(
    const bf16* __restrict__ QKV, bf16* __restrict__ O) {
  const int idx = blockIdx.x;
  const int qt = 15 - (idx >> 6);  // big q-tiles dispatch first
  const int bh = idx & 63;
  const int b = bh >> 4, h = bh & 15;
  const int t = threadIdx.x;
  const int lane = t & 63, wid = t >> 6;
  const int quad = lane >> 4, l16 = lane & 15;

  __shared__ bf16 sQ[128][72];
  __shared__ bf16 sK[64][72];
  __shared__ bf16 sVt[64][72];  // [hd][key ^ (hd&56)]
  __shared__ bf16 sP[4][16][72];

  const size_t qbase = (size_t)b * 2048 * 3072 + (size_t)h * 64;
  const int q0 = qt * 128;

  // stage Q tile (128 rows x 64)
  for (int c = t; c < 1024; c += 256) {
    int row = c >> 3, sub = (c & 7) * 8;
    *(bf16x8*)&sQ[row][sub] =
        *(const bf16x8*)(QKV + qbase + (size_t)(q0 + row) * 3072 + sub);
  }
  __syncthreads();

  bf16x8 aq[2][2];
#pragma unroll
  for (int mt = 0; mt < 2; ++mt)
#pragma unroll
    for (int ks = 0; ks < 2; ++ks)
      aq[mt][ks] =
          *(const bf16x8*)&sQ[wid * 32 + mt * 16 + l16][ks * 32 + quad * 8];

  float l_part[2][4] = {};
  floatx4 o_acc[2][4] = {};

  // staging pointers, bumped by one 64-row k-tile per iteration
  const int kr = t >> 3;          // 0..31
  const int sub = (t & 7) * 8;
  const bf16* pK0 = QKV + qbase + 1024 + (size_t)kr * 3072 + sub;
  const bf16* pK1 = pK0 + (size_t)32 * 3072;
  const int vr = kr * 2;          // 0..62 (even)
  const bf16* pV0 = QKV + qbase + 2048 + (size_t)vr * 3072 + sub;
  const bf16* pV1 = pV0 + 3072;
  const int vcol = vr ^ (sub & 56);
  const ptrdiff_t bump = (ptrdiff_t)64 * 3072;

  const int ktmax = 2 * qt + 1;
  for (int kt = 0; kt <= ktmax; ++kt) {
    __syncthreads();  // prior reads of sK/sVt done
    *(bf16x8*)&sK[kr][sub] = *(const bf16x8*)pK0;
    *(bf16x8*)&sK[32 + kr][sub] = *(const bf16x8*)pK1;
    bf16x8 va = *(const bf16x8*)pV0;
    bf16x8 vb = *(const bf16x8*)pV1;
#pragma unroll
    for (int j = 0; j < 8; ++j) {
      bf16x2 pk = {va[j], vb[j]};
      *(bf16x2*)&sVt[sub + j][vcol] = pk;  // (sub+j)&56 == sub
    }
    pK0 += bump; pK1 += bump; pV0 += bump; pV1 += bump;
    __syncthreads();

    // read B-fragments once; reuse across both mt passes
    bf16x8 bv[4][2];
#pragma unroll
    for (int nt = 0; nt < 4; ++nt) {
      const int r2 = nt * 16 + l16;
#pragma unroll
      for (int ks = 0; ks < 2; ++ks)
        bv[nt][ks] =
            *(const bf16x8*)&sVt[r2][(ks * 32 + quad * 8) ^ (r2 & 56)];
    }

    float p[2][4][4];
#pragma unroll
    for (int nt = 0; nt < 4; ++nt) {
      const int r2 = nt * 16 + l16;
      bf16x8 bk0 = *(const bf16x8*)&sK[r2][quad * 8];
      bf16x8 bk1 = *(const bf16x8*)&sK[r2][32 + quad * 8];
#pragma unroll
      for (int mt = 0; mt < 2; ++mt) {
        floatx4 acc = {};
        acc = __builtin_amdgcn_mfma_f32_16x16x32_bf16(aq[mt][0], bk0, acc, 0, 0, 0);
        acc = __builtin_amdgcn_mfma_f32_16x16x32_bf16(aq[mt][1], bk1, acc, 0, 0, 0);
#pragma unroll
        for (int r = 0; r < 4; ++r)
          p[mt][nt][r] = __builtin_exp2f(acc[r] * EXPC);
      }
    }

    // causal mask: only the last two k-tiles overlap this q-tile
    if (kt >= ktmax - 1) {
      const int k0 = kt * 64;
#pragma unroll
      for (int mt = 0; mt < 2; ++mt) {
        const int qrow_base = q0 + wid * 32 + mt * 16 + quad * 4;
#pragma unroll
        for (int nt = 0; nt < 4; ++nt) {
          const int kk = k0 + nt * 16 + l16;
#pragma unroll
          for (int r = 0; r < 4; ++r)
            if (kk > qrow_base + r) p[mt][nt][r] = 0.f;
        }
      }
    }

#pragma unroll
    for (int mt = 0; mt < 2; ++mt) {
#pragma unroll
      for (int nt = 0; nt < 4; ++nt)
#pragma unroll
        for (int r = 0; r < 4; ++r) {
          l_part[mt][r] += p[mt][nt][r];
          sP[wid][quad * 4 + r][nt * 16 + l16] = (bf16)p[mt][nt][r];
        }
      // same-wave LDS RAW/WAR ordered by lgkmcnt; sP[wid] is wave-private
      bf16x8 ap0 = *(const bf16x8*)&sP[wid][l16][quad * 8];
      bf16x8 ap1 = *(const bf16x8*)&sP[wid][l16][32 + quad * 8];
#pragma unroll
      for (int nt = 0; nt < 4; ++nt) {
        o_acc[mt][nt] = __builtin_amdgcn_mfma_f32_16x16x32_bf16(
            ap0, bv[nt][0], o_acc[mt][nt], 0, 0, 0);
        o_acc[mt][nt] = __builtin_amdgcn_mfma_f32_16x16x32_bf16(
            ap1, bv[nt][1], o_acc[mt][nt], 0, 0, 0);
      }
    }
  }

  // deferred l reduce (16 key-lanes) + write O
#pragma unroll
  for (int mt = 0; mt < 2; ++mt) {
#pragma unroll
    for (int off = 1; off < 16; off <<= 1)
#pragma unroll
      for (int r = 0; r < 4; ++r)
        l_part[mt][r] += __shfl_xor(l_part[mt][r], off);
    float inv[4];
#pragma unroll
    for (int r = 0; r < 4; ++r) inv[r] = 1.0f / l_part[mt][r];
#pragma unroll
    for (int nt = 0; nt < 4; ++nt)
#pragma unroll
      for (int r = 0; r < 4; ++r) {
        const size_t row =
            (size_t)b * 2048 + q0 + wid * 32 + mt * 16 + quad * 4 + r;
        const size_t col = (size_t)h * 64 + nt * 16 + l16;
        O[row * 1024 + col] = (bf16)(o_acc[mt][nt][r] * inv[r]);
      }
  }
}

// ---------------------------------------------------------------------------
// Launch
// ---------------------------------------------------------------------------
extern "C" void kernel_launch(void* const* d_in, const int* in_sizes, int n_in,
                              void* d_out, int out_size, void* d_ws, size_t ws_size,
                              hipStream_t stream) {
  const float* x = (const float*)d_in[0];
  const float* Wq = (const float*)d_in[1];
  const float* Wk = (const float*)d_in[2];
  const float* Wv = (const float*)d_in[3];
  const float* Wo = (const float*)d_in[4];
  const float* bo = (const float*)d_in[5];
  const float* W1 = (const float*)d_in[6];
  const float* b1 = (const float*)d_in[7];
  const float* W2 = (const float*)d_in[8];
  const float* b2 = (const float*)d_in[9];
  const float* gamma1 = (const float*)d_in[10];
  const float* beta1 = (const float*)d_in[11];
  const float* gamma2 = (const float*)d_in[12];
  const float* beta2 = (const float*)d_in[13];

  char* ws = (char*)d_ws;
  const size_t MB = (size_t)1 << 20;
  bf16* WqkvT = (bf16*)(ws + 0 * MB);
  bf16* WoT = (bf16*)(ws + 6 * MB);
  bf16* W1T = (bf16*)(ws + 8 * MB);
  bf16* W2T = (bf16*)(ws + 16 * MB);
  bf16* h1  = (bf16*)(ws + 24 * MB);
  bf16* QKVb = (bf16*)(ws + 40 * MB);
  bf16* attnb = (bf16*)(ws + 88 * MB);
  float* x1 = (float*)(ws + 104 * MB);
  bf16* h2  = (bf16*)(ws + 136 * MB);
  bf16* midb = (bf16*)(ws + 152 * MB);

  dim3 blk(256);

  transpose_cvt4<<<dim3(32, 32, 4), blk, 0, stream>>>(
      Wq, Wk, Wv, Wo, WqkvT, WqkvT + (size_t)1024 * 1024,
      WqkvT + (size_t)2048 * 1024, WoT, 1024, 1024);
  transpose_cvt<<<dim3(128, 32), blk, 0, stream>>>(W1, W1T, 1024, 4096);
  transpose_cvt<<<dim3(32, 128), blk, 0, stream>>>(W2, W2T, 4096, 1024);

  ln_kernel<<<8192, blk, 0, stream>>>(x, gamma1, beta1, h1);

  // fused QKV projection: [Q|K|V] = h1 @ [Wq|Wk|Wv]  (block-rich: BK=64)
  gemm_bt<3, 64><<<dim3(64, 24), blk, 0, stream>>>(h1, WqkvT, nullptr, nullptr,
                                                   QKVb, 8192, 3072, 1024);

  attn_kernel<<<dim3(1024), blk, 0, stream>>>(QKVb, attnb);

  // x1 = x + attn @ Wo + bo  (grid-starved: BK=128)
  gemm_bt<2, 128><<<dim3(64, 8), blk, 0, stream>>>(attnb, WoT, bo, x, x1,
                                                   8192, 1024, 1024);

  ln_kernel<<<8192, blk, 0, stream>>>(x1, gamma2, beta2, h2);

  // mid = gelu(h2 @ W1 + b1)  (block-rich: BK=64, fast gelu)
  gemm_bt<1, 64><<<dim3(64, 32), blk, 0, stream>>>(h2, W1T, b1, nullptr, midb,
                                                   8192, 4096, 1024);

  // out = x1 + mid @ W2 + b2  (grid-starved: BK=128)
  gemm_bt<2, 128><<<dim3(64, 8), blk, 0, stream>>>(midb, W2T, b2, x1, d_out,
                                                   8192, 1024, 4096);
}

// Round 8
// 452.836 us; speedup vs baseline: 1.0334x; 1.0334x over previous
//
#include <hip/hip_runtime.h>
#include <hip/hip_bf16.h>

// ---------------------------------------------------------------------------
// TransformerBlock: B=4, T=2048, D=1024, H=16, HD=64
// Round 8: attention was LDS-pipe + latency bound (103us; ~500 LDS-cyc per
// wave-step vs 14% MfmaUtil). Changes:
//  (1) V pre-transposed once into Vt[bh][d][t] -> K and V tiles stage via
//      global_load_lds DMA (SW=7 group swizzle, zero wave-issued LDS writes).
//  (2) QK computed as S^T (A=K, B=Q): P exits MFMA with lane=q, regs=4
//      consecutive keys -> sP relayout = 4 ds_write_b64 per mt (was 16 b16),
//      l-sum per-lane (2 shfl at end, none in loop).
//  (3) Q staged once via DMA (swizzled linear). LDS 41KB -> 3 blocks/CU.
// GEMMs unchanged (BK=64 block-rich / BK=128 grid-starved).
// ---------------------------------------------------------------------------

typedef __bf16 bf16;
typedef __attribute__((ext_vector_type(8))) __bf16 bf16x8;
typedef __attribute__((ext_vector_type(4))) __bf16 bf16x4;
typedef __attribute__((ext_vector_type(4))) float floatx4;

#define EXPC 0.18033688011112042f  // 0.125 * log2(e)

__device__ __forceinline__ void async_cp16(const bf16* g, bf16* l) {
  __builtin_amdgcn_global_load_lds(
      (const __attribute__((address_space(1))) void*)g,
      (__attribute__((address_space(3))) void*)l, 16, 0, 0);
}

// ---------------------------------------------------------------------------
// Transpose + convert: W (K x N fp32) -> WT (N x K bf16). z picks the matrix.
// ---------------------------------------------------------------------------
__global__ __launch_bounds__(256) void transpose_cvt4(
    const float* __restrict__ S0, const float* __restrict__ S1,
    const float* __restrict__ S2, const float* __restrict__ S3,
    bf16* __restrict__ D0, bf16* __restrict__ D1, bf16* __restrict__ D2,
    bf16* __restrict__ D3, int K, int N) {
  const float* W = (blockIdx.z == 0) ? S0 : (blockIdx.z == 1) ? S1
                   : (blockIdx.z == 2) ? S2 : S3;
  bf16* WT = (blockIdx.z == 0) ? D0 : (blockIdx.z == 1) ? D1
             : (blockIdx.z == 2) ? D2 : D3;
  __shared__ bf16 tile[32][33];
  const int tn = blockIdx.x;
  const int tk = blockIdx.y;
  const int t = threadIdx.x;
  const int row = t >> 3;
  const int c4 = (t & 7) * 4;

  const float* src = W + (size_t)(tk * 32 + row) * N + tn * 32 + c4;
  float4 v = *(const float4*)src;
  tile[row][c4 + 0] = (bf16)v.x;
  tile[row][c4 + 1] = (bf16)v.y;
  tile[row][c4 + 2] = (bf16)v.z;
  tile[row][c4 + 3] = (bf16)v.w;
  __syncthreads();
  bf16x4 o;
  o[0] = tile[c4 + 0][row];
  o[1] = tile[c4 + 1][row];
  o[2] = tile[c4 + 2][row];
  o[3] = tile[c4 + 3][row];
  *(bf16x4*)(WT + (size_t)(tn * 32 + row) * K + tk * 32 + c4) = o;
}

__global__ __launch_bounds__(256) void transpose_cvt(
    const float* __restrict__ W, bf16* __restrict__ WT, int K, int N) {
  __shared__ bf16 tile[32][33];
  const int tn = blockIdx.x;
  const int tk = blockIdx.y;
  const int t = threadIdx.x;
  const int row = t >> 3;
  const int c4 = (t & 7) * 4;

  const float* src = W + (size_t)(tk * 32 + row) * N + tn * 32 + c4;
  float4 v = *(const float4*)src;
  tile[row][c4 + 0] = (bf16)v.x;
  tile[row][c4 + 1] = (bf16)v.y;
  tile[row][c4 + 2] = (bf16)v.z;
  tile[row][c4 + 3] = (bf16)v.w;
  __syncthreads();
  bf16x4 o;
  o[0] = tile[c4 + 0][row];
  o[1] = tile[c4 + 1][row];
  o[2] = tile[c4 + 2][row];
  o[3] = tile[c4 + 3][row];
  *(bf16x4*)(WT + (size_t)(tn * 32 + row) * K + tk * 32 + c4) = o;
}

// ---------------------------------------------------------------------------
// V pre-transpose: V[t][d] (cols 2048.. of QKV) -> Vt[(bh*64+d)][t]
// ---------------------------------------------------------------------------
__global__ __launch_bounds__(256) void vtrans_kernel(
    const bf16* __restrict__ QKV, bf16* __restrict__ Vt) {
  const int tt = blockIdx.x;   // 0..31 t-tile
  const int bh = blockIdx.y;   // 0..63
  const int b = bh >> 4, h = bh & 15;
  __shared__ bf16 tile[64][72];
  const int t = threadIdx.x;
  const int row = t >> 3;          // 0..31
  const int c8 = (t & 7) * 8;
  const size_t vbase = (size_t)b * 2048 * 3072 + 2048 + (size_t)h * 64;
  const bf16* src = QKV + vbase + (size_t)(tt * 64 + row) * 3072 + c8;
  *(bf16x8*)&tile[row][c8] = *(const bf16x8*)src;
  *(bf16x8*)&tile[row + 32][c8] = *(const bf16x8*)(src + (size_t)32 * 3072);
  __syncthreads();
  bf16x8 o0, o1;
#pragma unroll
  for (int j = 0; j < 8; ++j) {
    o0[j] = tile[c8 + j][row];
    o1[j] = tile[c8 + j][row + 32];
  }
  bf16* dst = Vt + ((size_t)bh * 64 + row) * 2048 + tt * 64 + c8;
  *(bf16x8*)dst = o0;
  *(bf16x8*)(dst + (size_t)32 * 2048) = o1;
}

// ---------------------------------------------------------------------------
// LayerNorm: one block per row of 1024. fp32 in -> bf16 out.
// ---------------------------------------------------------------------------
__global__ __launch_bounds__(256) void ln_kernel(
    const float* __restrict__ x, const float* __restrict__ gamma,
    const float* __restrict__ beta, bf16* __restrict__ out) {
  const int row = blockIdx.x;
  const int t = threadIdx.x;
  const float* xr = x + (size_t)row * 1024;
  float4 v4 = *(const float4*)(xr + t * 4);
  float a[4] = {v4.x, v4.y, v4.z, v4.w};
  float s = a[0] + a[1] + a[2] + a[3];
  float ss = a[0] * a[0] + a[1] * a[1] + a[2] * a[2] + a[3] * a[3];
  for (int off = 1; off < 64; off <<= 1) {
    s += __shfl_xor(s, off);
    ss += __shfl_xor(ss, off);
  }
  __shared__ float red[8];
  const int wid = t >> 6, lane = t & 63;
  if (lane == 0) { red[wid] = s; red[wid + 4] = ss; }
  __syncthreads();
  s = red[0] + red[1] + red[2] + red[3];
  ss = red[4] + red[5] + red[6] + red[7];
  const float mean = s * (1.0f / 1024.0f);
  const float var = ss * (1.0f / 1024.0f) - mean * mean;
  const float rstd = rsqrtf(var + 1e-5f);
  bf16x4 o;
  for (int j = 0; j < 4; ++j) {
    float g = gamma[t * 4 + j];
    float b = beta[t * 4 + j];
    o[j] = (bf16)((a[j] - mean) * rstd * g + b);
  }
  *(bf16x4*)(out + (size_t)row * 1024 + t * 4) = o;
}

// fast exact-form tanh-gelu: gelu = x*t/(t+1), t = e^{2u}.
__device__ __forceinline__ float gelu_f(float x) {
  const float c = 0.7978845608028654f;
  float u = c * (x + 0.044715f * x * x * x);
  u = fminf(fmaxf(u, -10.0f), 10.0f);
  float t = __builtin_exp2f(u * 2.8853900817779268f);  // e^{2u}
  return x * t * __builtin_amdgcn_rcpf(t + 1.0f);
}

// ---------------------------------------------------------------------------
// GEMM (256 thr, 4 waves 2x2, each 64x64): C[M,N] = A[M,K] @ BT[N,K]^T.
// 128x128 tile, templated BK: 64 block-rich (3 blocks/CU), 128 grid-starved.
// BK>=64: 16B groups XOR-swizzled via the global gather (LDS dst linear).
// MODE 1: bf16 = gelu(C+bias); MODE 2: f32 = C+bias+resid; MODE 3: bf16 = C.
// ---------------------------------------------------------------------------
template <int MODE, int BK>
__global__ __launch_bounds__(256, 2) void gemm_bt(
    const bf16* __restrict__ A, const bf16* __restrict__ BT,
    const float* __restrict__ bias, const float* __restrict__ resid,
    void* __restrict__ out, int M, int N, int K) {
  __shared__ bf16 sA[128 * BK];
  __shared__ bf16 sB[128 * BK];
  constexpr int GPR = BK / 8;
  constexpr int CPT = GPR / 2;
  constexpr int RPI = 256 / GPR;
  constexpr int SW = (BK >= 64) ? 7 : 0;

  const int t = threadIdx.x;
  const int lane = t & 63, wid = t >> 6;
  const int waveM = wid >> 1, waveN = wid & 1;
  const int quad = lane >> 4, l16 = lane & 15;
  const size_t m0 = (size_t)blockIdx.x * 128;
  const size_t n0 = (size_t)blockIdx.y * 128;

  floatx4 acc[4][4] = {};

  const int r0 = t / GPR;
  const int gp = t % GPR;
  const int gsrc = gp ^ (r0 & SW);
  const bf16* Ag = A + (m0 + r0) * (size_t)K + gsrc * 8;
  const bf16* Bg = BT + (n0 + r0) * (size_t)K + gsrc * 8;
  bf16* sAp = sA + t * 8;
  bf16* sBp = sB + t * 8;

  for (int k0 = 0; k0 < K; k0 += BK) {
    __syncthreads();
#pragma unroll
    for (int it = 0; it < CPT; ++it) {
      async_cp16(Ag + k0 + (size_t)(it * RPI) * K, sAp + it * 2048);
      async_cp16(Bg + k0 + (size_t)(it * RPI) * K, sBp + it * 2048);
    }
    __syncthreads();
#pragma unroll
    for (int ks = 0; ks < BK / 32; ++ks) {
      bf16x8 af[4], bfv[4];
#pragma unroll
      for (int i = 0; i < 4; ++i) {
        const int rowA = waveM * 64 + i * 16 + l16;
        const int g = ((ks * 4 + quad) ^ (l16 & SW)) * 8;
        af[i] = *(const bf16x8*)&sA[rowA * BK + g];
        const int rowB = waveN * 64 + i * 16 + l16;
        bfv[i] = *(const bf16x8*)&sB[rowB * BK + g];
      }
#pragma unroll
      for (int mt = 0; mt < 4; ++mt)
#pragma unroll
        for (int nt = 0; nt < 4; ++nt)
          acc[mt][nt] = __builtin_amdgcn_mfma_f32_16x16x32_bf16(
              af[mt], bfv[nt], acc[mt][nt], 0, 0, 0);
    }
  }

#pragma unroll
  for (int mt = 0; mt < 4; ++mt) {
#pragma unroll
    for (int nt = 0; nt < 4; ++nt) {
      const size_t row_base = m0 + waveM * 64 + mt * 16 + quad * 4;
      const size_t col = n0 + waveN * 64 + nt * 16 + l16;
#pragma unroll
      for (int r = 0; r < 4; ++r) {
        const size_t row = row_base + r;
        float v = acc[mt][nt][r];
        if (MODE == 1) {
          v = gelu_f(v + bias[col]);
          ((bf16*)out)[row * N + col] = (bf16)v;
        } else if (MODE == 2) {
          v += bias[col] + resid[row * N + col];
          ((float*)out)[row * N + col] = v;
        } else {
          ((bf16*)out)[row * N + col] = (bf16)v;
        }
      }
    }
  }
}

// ---------------------------------------------------------------------------
// Flash-style causal attention, QT=128, S^T orientation, DMA staging.
// Per wave: 32 q-rows (2 mt). QK as S^T = K-frag x Q-frag: C-layout gives
// lane=q, regs=4 consecutive keys -> sP written as b64, l-sum per-lane.
// K from QKV rows, V from pre-transposed Vt rows, both DMA'd with SW=7
// group swizzle (dst linear). LDS: sQ 16K + sK 8K + sV 8K + sP 9K = 41KB.
// ---------------------------------------------------------------------------
__global__ __launch_bounds__(256) void attn_kernel(
    const bf16* __restrict__ QKV, const bf16* __restrict__ Vt,
    bf16* __restrict__ O) {
  const int idx = blockIdx.x;
  const int qt = 15 - (idx >> 6);  // big q-tiles dispatch first
  const int bh = idx & 63;
  const int b = bh >> 4, h = bh & 15;
  const int t = threadIdx.x;
  const int lane = t & 63, wid = t >> 6;
  const int quad = lane >> 4, l16 = lane & 15;

  __shared__ bf16 sQ[128 * 64];   // swizzled rows (q-major)
  __shared__ bf16 sK[64 * 64];    // swizzled rows (key-major)
  __shared__ bf16 sV[64 * 64];    // swizzled rows (d-major, from Vt)
  __shared__ bf16 sP[4][16][72];  // [wave][q][key]

  const size_t qkvbase = (size_t)b * 2048 * 3072 + (size_t)h * 64;
  const int q0 = qt * 128;

  const int r0 = t >> 3;   // 0..31
  const int gp = t & 7;
  const int gsw = gp ^ (r0 & 7);  // (r0+32)&7 == r0&7: same for both halves

  // one-time Q stage via DMA (128 rows x 64)
  {
    const bf16* pQ = QKV + qkvbase + (size_t)(q0 + r0) * 3072 + gsw * 8;
#pragma unroll
    for (int j = 0; j < 4; ++j)
      async_cp16(pQ + (size_t)(j * 32) * 3072, sQ + j * 2048 + t * 8);
  }

  // K/V staging pointers (bumped per k-tile)
  const bf16* pK = QKV + qkvbase + 1024 + (size_t)r0 * 3072 + gsw * 8;
  const bf16* pV = Vt + ((size_t)bh * 64 + r0) * 2048 + gsw * 8;
  const ptrdiff_t bumpK = (ptrdiff_t)64 * 3072;

  __syncthreads();  // drain Q DMA

  // Q B-fragments: lane n=q, k-chunk = d
  bf16x8 aq[2][2];
#pragma unroll
  for (int mt = 0; mt < 2; ++mt) {
    const int row = wid * 32 + mt * 16 + l16;
#pragma unroll
    for (int ks = 0; ks < 2; ++ks)
      aq[mt][ks] =
          *(const bf16x8*)&sQ[row * 64 + (((ks * 4 + quad) ^ (row & 7)) * 8)];
  }

  float l_part[2] = {0.f, 0.f};
  floatx4 o_acc[2][4] = {};

  const int ktmax = 2 * qt + 1;
  for (int kt = 0; kt <= ktmax; ++kt) {
    __syncthreads();  // prior reads of sK/sV done
    async_cp16(pK, sK + t * 8);
    async_cp16(pK + (size_t)32 * 3072, sK + 2048 + t * 8);
    async_cp16(pV, sV + t * 8);
    async_cp16(pV + (size_t)32 * 2048, sV + 2048 + t * 8);
    pK += bumpK;
    pV += 64;
    __syncthreads();  // drain DMA

    // V B-fragments (lane n=d), read once, reused across mt
    bf16x8 bv[4][2];
#pragma unroll
    for (int nt = 0; nt < 4; ++nt) {
      const int d = nt * 16 + l16;
#pragma unroll
      for (int ks = 0; ks < 2; ++ks)
        bv[nt][ks] =
            *(const bf16x8*)&sV[d * 64 + (((ks * 4 + quad) ^ (d & 7)) * 8)];
    }

    // S^T = K-frag x Q-frag: D rows = keys, cols = q
    float p[2][4][4];
#pragma unroll
    for (int nt = 0; nt < 4; ++nt) {
      const int kr = nt * 16 + l16;
      bf16x8 bk0 = *(const bf16x8*)&sK[kr * 64 + ((quad ^ (kr & 7)) * 8)];
      bf16x8 bk1 = *(const bf16x8*)&sK[kr * 64 + (((4 + quad) ^ (kr & 7)) * 8)];
#pragma unroll
      for (int mt = 0; mt < 2; ++mt) {
        floatx4 acc = {};
        acc = __builtin_amdgcn_mfma_f32_16x16x32_bf16(bk0, aq[mt][0], acc, 0, 0, 0);
        acc = __builtin_amdgcn_mfma_f32_16x16x32_bf16(bk1, aq[mt][1], acc, 0, 0, 0);
#pragma unroll
        for (int r = 0; r < 4; ++r)
          p[mt][nt][r] = __builtin_exp2f(acc[r] * EXPC);
      }
    }

    // causal mask on the last two k-tiles: zero where key > q
    if (kt >= ktmax - 1) {
      const int k0 = kt * 64;
#pragma unroll
      for (int mt = 0; mt < 2; ++mt) {
        const int qg = q0 + wid * 32 + mt * 16 + l16;
#pragma unroll
        for (int nt = 0; nt < 4; ++nt) {
          const int kg = k0 + nt * 16 + quad * 4;
#pragma unroll
          for (int r = 0; r < 4; ++r)
            if (kg + r > qg) p[mt][nt][r] = 0.f;
        }
      }
    }

#pragma unroll
    for (int mt = 0; mt < 2; ++mt) {
      // P -> sP: lane (quad,l16) holds P[q=l16][key=nt*16+quad*4+r] -> b64
#pragma unroll
      for (int nt = 0; nt < 4; ++nt) {
        bf16x4 pk;
#pragma unroll
        for (int r = 0; r < 4; ++r) {
          l_part[mt] += p[mt][nt][r];
          pk[r] = (bf16)p[mt][nt][r];
        }
        *(bf16x4*)&sP[wid][l16][nt * 16 + quad * 4] = pk;
      }
      // A-frag for PV (same-wave LDS ordering; sP[wid] wave-private)
      bf16x8 ap0 = *(const bf16x8*)&sP[wid][l16][quad * 8];
      bf16x8 ap1 = *(const bf16x8*)&sP[wid][l16][32 + quad * 8];
#pragma unroll
      for (int nt = 0; nt < 4; ++nt) {
        o_acc[mt][nt] = __builtin_amdgcn_mfma_f32_16x16x32_bf16(
            ap0, bv[nt][0], o_acc[mt][nt], 0, 0, 0);
        o_acc[mt][nt] = __builtin_amdgcn_mfma_f32_16x16x32_bf16(
            ap1, bv[nt][1], o_acc[mt][nt], 0, 0, 0);
      }
    }
  }

  // l reduce (across quads) + broadcast to o_acc rows + write O
#pragma unroll
  for (int mt = 0; mt < 2; ++mt) {
    float lt = l_part[mt];
    lt += __shfl_xor(lt, 16);
    lt += __shfl_xor(lt, 32);  // every lane: total for q = wid*32+mt*16+l16
    float inv[4];
#pragma unroll
    for (int r = 0; r < 4; ++r)
      inv[r] = 1.0f / __shfl(lt, quad * 4 + r);  // l for q-row quad*4+r
#pragma unroll
    for (int nt = 0; nt < 4; ++nt)
#pragma unroll
      for (int r = 0; r < 4; ++r) {
        const size_t row =
            (size_t)b * 2048 + q0 + wid * 32 + mt * 16 + quad * 4 + r;
        const size_t col = (size_t)h * 64 + nt * 16 + l16;
        O[row * 1024 + col] = (bf16)(o_acc[mt][nt][r] * inv[r]);
      }
  }
}

// ---------------------------------------------------------------------------
// Launch
// ---------------------------------------------------------------------------
extern "C" void kernel_launch(void* const* d_in, const int* in_sizes, int n_in,
                              void* d_out, int out_size, void* d_ws, size_t ws_size,
                              hipStream_t stream) {
  const float* x = (const float*)d_in[0];
  const float* Wq = (const float*)d_in[1];
  const float* Wk = (const float*)d_in[2];
  const float* Wv = (const float*)d_in[3];
  const float* Wo = (const float*)d_in[4];
  const float* bo = (const float*)d_in[5];
  const float* W1 = (const float*)d_in[6];
  const float* b1 = (const float*)d_in[7];
  const float* W2 = (const float*)d_in[8];
  const float* b2 = (const float*)d_in[9];
  const float* gamma1 = (const float*)d_in[10];
  const float* beta1 = (const float*)d_in[11];
  const float* gamma2 = (const float*)d_in[12];
  const float* beta2 = (const float*)d_in[13];

  char* ws = (char*)d_ws;
  const size_t MB = (size_t)1 << 20;
  bf16* WqkvT = (bf16*)(ws + 0 * MB);
  bf16* WoT = (bf16*)(ws + 6 * MB);
  bf16* W1T = (bf16*)(ws + 8 * MB);
  bf16* W2T = (bf16*)(ws + 16 * MB);
  bf16* h1  = (bf16*)(ws + 24 * MB);   // reused as Vt after QKV GEMM
  bf16* Vt  = (bf16*)(ws + 24 * MB);   // 64*64*2048*2 = 16MB
  bf16* QKVb = (bf16*)(ws + 40 * MB);
  bf16* attnb = (bf16*)(ws + 88 * MB);
  float* x1 = (float*)(ws + 104 * MB);
  bf16* h2  = (bf16*)(ws + 136 * MB);
  bf16* midb = (bf16*)(ws + 152 * MB);

  dim3 blk(256);

  transpose_cvt4<<<dim3(32, 32, 4), blk, 0, stream>>>(
      Wq, Wk, Wv, Wo, WqkvT, WqkvT + (size_t)1024 * 1024,
      WqkvT + (size_t)2048 * 1024, WoT, 1024, 1024);
  transpose_cvt<<<dim3(128, 32), blk, 0, stream>>>(W1, W1T, 1024, 4096);
  transpose_cvt<<<dim3(32, 128), blk, 0, stream>>>(W2, W2T, 4096, 1024);

  ln_kernel<<<8192, blk, 0, stream>>>(x, gamma1, beta1, h1);

  // fused QKV projection: [Q|K|V] = h1 @ [Wq|Wk|Wv]  (block-rich: BK=64)
  gemm_bt<3, 64><<<dim3(64, 24), blk, 0, stream>>>(h1, WqkvT, nullptr, nullptr,
                                                   QKVb, 8192, 3072, 1024);

  // V -> Vt (overwrites h1, which is dead after the QKV GEMM)
  vtrans_kernel<<<dim3(32, 64), blk, 0, stream>>>(QKVb, Vt);

  attn_kernel<<<dim3(1024), blk, 0, stream>>>(QKVb, Vt, attnb);

  // x1 = x + attn @ Wo + bo  (grid-starved: BK=128)
  gemm_bt<2, 128><<<dim3(64, 8), blk, 0, stream>>>(attnb, WoT, bo, x, x1,
                                                   8192, 1024, 1024);

  ln_kernel<<<8192, blk, 0, stream>>>(x1, gamma2, beta2, h2);

  // mid = gelu(h2 @ W1 + b1)  (block-rich: BK=64, fast gelu)
  gemm_bt<1, 64><<<dim3(64, 32), blk, 0, stream>>>(h2, W1T, b1, nullptr, midb,
                                                   8192, 4096, 1024);

  // out = x1 + mid @ W2 + b2  (grid-starved: BK=128)
  gemm_bt<2, 128><<<dim3(64, 8), blk, 0, stream>>>(midb, W2T, b2, x1, d_out,
                                                   8192, 1024, 4096);
}